// Round 6
// baseline (203.608 us; speedup 1.0000x reference)
//
#include <hip/hip_runtime.h>

#define B_ 2
#define D_ 1024
#define T_ 2048
#define H_ 16
#define DH_ 64
#define BH_ (B_ * H_)

typedef __attribute__((ext_vector_type(8))) short bf16x8;
typedef __attribute__((ext_vector_type(8))) unsigned short u16x8;
typedef __attribute__((ext_vector_type(4))) float f32x4;

// float -> bf16 (RNE) as raw ushort
__device__ __forceinline__ unsigned short f2bf(float f) {
    unsigned u = __float_as_uint(f);
    u += 0x7fffu + ((u >> 16) & 1u);
    return (unsigned short)(u >> 16);
}

// ---------------------------------------------------------------------------
// Kernel T1: x (B,D,T) fp32 -> xT (B,T,D) bf16.  64x64 tiles through LDS.
// ---------------------------------------------------------------------------
__global__ __launch_bounds__(256) void xpose_kernel(
    const float* __restrict__ x, unsigned short* __restrict__ xT)
{
    __shared__ __align__(16) unsigned short Ls[64][68];
    const int t0 = blockIdx.x * 64;
    const int d0 = blockIdx.y * 64;
    const int b  = blockIdx.z;
    const int tid = threadIdx.x;

    const float* xb = x + (size_t)b * D_ * T_ + (size_t)d0 * T_ + t0;
    #pragma unroll
    for (int p = 0; p < 4; p++) {
        int i4  = tid + p * 256;
        int row = i4 >> 4;            // d
        int c4  = (i4 & 15) << 2;     // t
        float4 v = *(const float4*)(xb + (size_t)row * T_ + c4);
        ushort4 u;
        u.x = f2bf(v.x); u.y = f2bf(v.y); u.z = f2bf(v.z); u.w = f2bf(v.w);
        *(ushort4*)&Ls[row][c4] = u;
    }
    __syncthreads();
    unsigned short* ob = xT + (size_t)b * T_ * D_ + (size_t)t0 * D_ + d0;
    #pragma unroll
    for (int p = 0; p < 2; p++) {
        int i    = tid + p * 256;
        int orow = i >> 3;            // t
        int oc8  = (i & 7) * 8;       // d
        u16x8 tv;
        #pragma unroll
        for (int j = 0; j < 8; j++) tv[j] = Ls[oc8 + j][orow];
        *(u16x8*)(ob + (size_t)orow * D_ + oc8) = tv;
    }
}

// ---------------------------------------------------------------------------
// Kernel T2: w (3,H,D,Dh) fp32 -> wT (3,H,Dh,D) bf16.  64x64 tiles.
// ---------------------------------------------------------------------------
__global__ __launch_bounds__(256) void wpose_kernel(
    const float* __restrict__ w, unsigned short* __restrict__ wT)
{
    __shared__ __align__(16) unsigned short Ls[64][68];
    const int d0 = blockIdx.x * 64;
    const int nh = blockIdx.y;        // 0..47
    const int tid = threadIdx.x;

    const float* wb = w + (size_t)nh * D_ * DH_ + (size_t)d0 * DH_;
    #pragma unroll
    for (int p = 0; p < 4; p++) {
        int i4  = tid + p * 256;
        int row = i4 >> 4;            // d
        int c4  = (i4 & 15) << 2;     // dh
        float4 v = *(const float4*)(wb + (size_t)row * DH_ + c4);
        ushort4 u;
        u.x = f2bf(v.x); u.y = f2bf(v.y); u.z = f2bf(v.z); u.w = f2bf(v.w);
        *(ushort4*)&Ls[row][c4] = u;
    }
    __syncthreads();
    unsigned short* ob = wT + (size_t)nh * DH_ * D_ + d0;
    #pragma unroll
    for (int p = 0; p < 2; p++) {
        int i    = tid + p * 256;
        int orow = i >> 3;            // dh
        int oc8  = (i & 7) * 8;       // d
        u16x8 tv;
        #pragma unroll
        for (int j = 0; j < 8; j++) tv[j] = Ls[oc8 + j][orow];
        *(u16x8*)(ob + (size_t)orow * D_ + oc8) = tv;
    }
}

// ---------------------------------------------------------------------------
// Kernel G: QKV projection via bf16 MFMA, 128(t) x 128(dh = 2 heads) tiles.
// q outputs pre-scaled by 0.125 (exact). q,k -> qk[n][bh][t][dh];
// v -> vT[bh][dh][t] directly (transposed read-out of the LDS epilogue tile),
// eliminating the separate vpose kernel.
// ---------------------------------------------------------------------------
#define LX 72

__global__ __launch_bounds__(256) void proj_mfma_kernel(
    const unsigned short* __restrict__ xT, const unsigned short* __restrict__ wT,
    unsigned short* __restrict__ qk, unsigned short* __restrict__ vT)
{
    __shared__ __align__(16) unsigned short Buf[18432];  // 36864 B
    unsigned short* Xs = Buf;          // [128][72]
    unsigned short* Ws = Buf + 9216;   // [128][72]
    unsigned short* Es = Buf;          // [128][136] epilogue

    const int t0 = blockIdx.x * 128;
    const int y  = blockIdx.y;        // n*16 + b*8 + hp
    const int n  = y >> 4;
    const int b  = (y >> 3) & 1;
    const int hp = y & 7;             // head pair: heads 2hp, 2hp+1

    const unsigned short* xb = xT + (size_t)b * T_ * D_ + (size_t)t0 * D_;
    const unsigned short* wb = wT + (size_t)(n * 16 + 2 * hp) * DH_ * D_;

    const int tid  = threadIdx.x;
    const int wv   = tid >> 6;
    const int lane = tid & 63;
    const int c15  = lane & 15;
    const int quad = lane >> 4;
    const int tq   = (wv & 1) * 64;   // wave's t base
    const int dq   = (wv >> 1) * 64;  // wave's dh base

    f32x4 acc[4][4];
    #pragma unroll
    for (int mt = 0; mt < 4; mt++)
        #pragma unroll
        for (int nt = 0; nt < 4; nt++)
            acc[mt][nt] = (f32x4){0.f, 0.f, 0.f, 0.f};

    for (int k0 = 0; k0 < D_; k0 += 64) {
        __syncthreads();
        #pragma unroll
        for (int p = 0; p < 4; p++) {
            int i    = tid + p * 256;
            int row  = i >> 3;            // 0..127
            int col8 = (i & 7) * 8;
            *(u16x8*)&Xs[row * LX + col8] =
                *(const u16x8*)(xb + (size_t)row * D_ + k0 + col8);
            *(u16x8*)&Ws[row * LX + col8] =
                *(const u16x8*)(wb + (size_t)row * D_ + k0 + col8);
        }
        __syncthreads();

        bf16x8 af[4][2], bf[4][2];
        #pragma unroll
        for (int mt = 0; mt < 4; mt++)
            #pragma unroll
            for (int s = 0; s < 2; s++)
                af[mt][s] = *(bf16x8*)&Xs[(tq + mt * 16 + c15) * LX + quad * 8 + s * 32];
        #pragma unroll
        for (int nt = 0; nt < 4; nt++)
            #pragma unroll
            for (int s = 0; s < 2; s++)
                bf[nt][s] = *(bf16x8*)&Ws[(dq + nt * 16 + c15) * LX + quad * 8 + s * 32];

        #pragma unroll
        for (int mt = 0; mt < 4; mt++)
            #pragma unroll
            for (int nt = 0; nt < 4; nt++)
                #pragma unroll
                for (int s = 0; s < 2; s++)
                    acc[mt][nt] = __builtin_amdgcn_mfma_f32_16x16x32_bf16(
                        af[mt][s], bf[nt][s], acc[mt][nt], 0, 0, 0);
    }

    const float scale = (n == 0) ? 0.125f : 1.0f;   // fold 1/sqrt(Dh) into q
    __syncthreads();   // done reading Xs/Ws
    #pragma unroll
    for (int mt = 0; mt < 4; mt++)
        #pragma unroll
        for (int nt = 0; nt < 4; nt++)
            #pragma unroll
            for (int r = 0; r < 4; r++)
                Es[(tq + mt * 16 + quad * 4 + r) * 136 + dq + nt * 16 + c15] =
                    f2bf(acc[mt][nt][r] * scale);
    __syncthreads();

    if (n < 2) {
        #pragma unroll
        for (int p = 0; p < 8; p++) {
            int i    = tid + p * 256;
            int row  = i >> 4;            // t 0..127
            int col8 = (i & 15) * 8;      // dh 0..120
            int head = col8 >> 6;
            unsigned short* ob = qk +
                ((size_t)(n * 32 + b * 16 + 2 * hp + head) * T_ + t0 + row) * DH_ + (col8 & 63);
            *(u16x8*)ob = *(u16x8*)&Es[row * 136 + col8];
        }
    } else {
        // v: transposed read-out -> vT[bh][dh][t]
        #pragma unroll
        for (int p = 0; p < 8; p++) {
            int i    = tid + p * 256;
            int orow = i >> 4;            // dh 0..127
            int oc8  = (i & 15) * 8;      // t 0..120
            int head = orow >> 6;
            u16x8 tv;
            #pragma unroll
            for (int j = 0; j < 8; j++) tv[j] = Es[(oc8 + j) * 136 + orow];
            unsigned short* ob = vT +
                (size_t)(b * 16 + 2 * hp + head) * DH_ * T_ +
                (size_t)(orow & 63) * T_ + t0 + oc8;
            *(u16x8*)ob = tv;
        }
    }
}

// ---------------------------------------------------------------------------
// Kernel A: flash attention, bf16 MFMA, fixed-max softmax.
// 128-query blocks; wave owns 32 q (2 groups of 16, qrow = lane&15 per group).
// S^T = K*Q^T: A=K fragments (b128 from Ks), B=Q^T (b128 direct from global,
// loaded once). S^T C-layout gives 4 consecutive keys per lane -> P written
// as packed b64; PV reads P as contiguous b128 A-fragments from per-wave Ps.
// V from vT[dh][t] -> b128 B-fragments. All LDS accesses wide, 2-way max.
// ---------------------------------------------------------------------------
#define LQ 72

__global__ __launch_bounds__(256) void attn_mfma_kernel(
    const unsigned short* __restrict__ qk, const unsigned short* __restrict__ vT,
    float* __restrict__ out)
{
    __shared__ __align__(16) unsigned char smem[37376];
    unsigned short* Ks  = (unsigned short*)smem;            // [64][72]
    unsigned short* Vs  = (unsigned short*)(smem + 9216);   // [64][72] row=dh
    unsigned short* Psb = (unsigned short*)(smem + 18432);  // 4 x [32][72]
    float*          Os  = (float*)smem;                     // [64][132] epilogue
    float*          Lrow = (float*)(smem + 36864);          // [128]

    const int t0 = blockIdx.x * 128;
    const int bh = blockIdx.y;

    const unsigned short* qg = qk + ((size_t)bh * T_ + t0) * DH_;       // pre-scaled q
    const unsigned short* kg = qk + ((size_t)(BH_ + bh) * T_) * DH_;
    const unsigned short* vg = vT + (size_t)bh * DH_ * T_;              // [dh][t]

    const int tid  = threadIdx.x;
    const int wv   = tid >> 6;
    const int lane = tid & 63;
    const int c15  = lane & 15;
    const int quad = lane >> 4;

    unsigned short* Ps = Psb + wv * 2304;   // this wave's [32][72]

    // Q^T B-fragments straight from global (row = wave's qrow, cols = dh)
    bf16x8 bq[2][2];
    #pragma unroll
    for (int g = 0; g < 2; g++)
        #pragma unroll
        for (int s = 0; s < 2; s++)
            bq[g][s] = *(const bf16x8*)(qg +
                (size_t)(wv * 32 + g * 16 + c15) * DH_ + quad * 8 + s * 32);

    float lsum[2] = {0.f, 0.f};
    f32x4 Oacc[2][4];
    #pragma unroll
    for (int g = 0; g < 2; g++)
        #pragma unroll
        for (int nt = 0; nt < 4; nt++)
            Oacc[g][nt] = (f32x4){0.f, 0.f, 0.f, 0.f};

    for (int tau = 0; tau < T_; tau += 64) {
        __syncthreads();   // A: previous iteration's readers done
        #pragma unroll
        for (int p = 0; p < 2; p++) {
            int i    = tid + p * 256;
            int row  = i >> 3;            // 0..63
            int col8 = (i & 7) * 8;
            *(u16x8*)&Ks[row * LQ + col8] =
                *(const u16x8*)(kg + (size_t)(tau + row) * DH_ + col8);
            *(u16x8*)&Vs[row * LQ + col8] =
                *(const u16x8*)(vg + (size_t)row * T_ + tau + col8);
        }
        __syncthreads();   // B: tiles staged

        // K A-fragments (shared across both q-groups)
        bf16x8 ak[4][2];
        #pragma unroll
        for (int mt = 0; mt < 4; mt++)
            #pragma unroll
            for (int s = 0; s < 2; s++)
                ak[mt][s] = *(bf16x8*)&Ks[(mt * 16 + c15) * LQ + quad * 8 + s * 32];

        // S^T = K Q^T; exp; packed b64 P writes
        #pragma unroll
        for (int g = 0; g < 2; g++) {
            #pragma unroll
            for (int mt = 0; mt < 4; mt++) {
                f32x4 sa = (f32x4){0.f, 0.f, 0.f, 0.f};
                #pragma unroll
                for (int s = 0; s < 2; s++)
                    sa = __builtin_amdgcn_mfma_f32_16x16x32_bf16(ak[mt][s], bq[g][s], sa, 0, 0, 0);
                float p0 = __expf(sa[0]);
                float p1 = __expf(sa[1]);
                float p2 = __expf(sa[2]);
                float p3 = __expf(sa[3]);
                lsum[g] += (p0 + p1) + (p2 + p3);
                uint2 pk;
                pk.x = (unsigned)f2bf(p0) | ((unsigned)f2bf(p1) << 16);
                pk.y = (unsigned)f2bf(p2) | ((unsigned)f2bf(p3) << 16);
                *(uint2*)&Ps[(g * 16 + c15) * LQ + mt * 16 + quad * 4] = pk;
            }
        }
        __syncthreads();   // C: P visible (also orders Vs reads below)

        // O += P V : A = P rows (b128 from own-wave Ps), B = V^T fragments
        bf16x8 bv[4][2];
        #pragma unroll
        for (int nt = 0; nt < 4; nt++)
            #pragma unroll
            for (int s = 0; s < 2; s++)
                bv[nt][s] = *(bf16x8*)&Vs[(nt * 16 + c15) * LQ + quad * 8 + s * 32];
        #pragma unroll
        for (int g = 0; g < 2; g++)
            #pragma unroll
            for (int s = 0; s < 2; s++) {
                bf16x8 ap = *(bf16x8*)&Ps[(g * 16 + c15) * LQ + quad * 8 + s * 32];
                #pragma unroll
                for (int nt = 0; nt < 4; nt++)
                    Oacc[g][nt] = __builtin_amdgcn_mfma_f32_16x16x32_bf16(
                        ap, bv[nt][s], Oacc[g][nt], 0, 0, 0);
            }
    }

    // epilogue: reduce row sums across the 4 quads, share via LDS
    #pragma unroll
    for (int g = 0; g < 2; g++) {
        lsum[g] += __shfl_xor(lsum[g], 16);
        lsum[g] += __shfl_xor(lsum[g], 32);
    }
    if (lane < 16) {
        Lrow[wv * 32 + lane]      = lsum[0];
        Lrow[wv * 32 + 16 + lane] = lsum[1];
    }
    __syncthreads();   // all PV reads done + Lrow visible

    #pragma unroll
    for (int g = 0; g < 2; g++) {
        float linv[4];
        #pragma unroll
        for (int r = 0; r < 4; r++)
            linv[r] = 1.0f / Lrow[wv * 32 + g * 16 + quad * 4 + r];
        #pragma unroll
        for (int nt = 0; nt < 4; nt++)
            #pragma unroll
            for (int r = 0; r < 4; r++)
                Os[(nt * 16 + c15) * 132 + wv * 32 + g * 16 + quad * 4 + r] =
                    Oacc[g][nt][r] * linv[r];
    }
    __syncthreads();

    const int b = bh >> 4, h = bh & 15;
    float* og = out + (size_t)b * D_ * T_ + (size_t)(h * DH_) * T_ + t0;
    #pragma unroll
    for (int p = 0; p < 8; p++) {
        int i   = tid + p * 256;
        int row = i >> 5;             // dh 0..63
        int c4  = (i & 31) << 2;      // t offset 0..124
        *(float4*)(og + (size_t)row * T_ + c4) = *(float4*)&Os[row * 132 + c4];
    }
}

extern "C" void kernel_launch(void* const* d_in, const int* in_sizes, int n_in,
                              void* d_out, int out_size, void* d_ws, size_t ws_size,
                              hipStream_t stream)
{
    const float* x = (const float*)d_in[0];   // (B, D, T) fp32
    const float* w = (const float*)d_in[1];   // (3, H, D, Dh) fp32
    float* out = (float*)d_out;               // (B, D, T) fp32

    // ws layout:
    unsigned short* qk = (unsigned short*)d_ws;                           // [2][32][T][64] bf16 = 16 MB (+8 MB slack)
    unsigned short* vT = (unsigned short*)((char*)d_ws + (24u << 20));    // [32][64][T] bf16 = 8 MB
    unsigned short* xT = (unsigned short*)((char*)d_ws + (32u << 20));    // [B][T][D] bf16 = 8 MB
    unsigned short* wT = (unsigned short*)((char*)d_ws + (40u << 20));    // [3][H][64][D] bf16 = 6 MB

    xpose_kernel<<<dim3(T_ / 64, D_ / 64, B_), 256, 0, stream>>>(x, xT);
    wpose_kernel<<<dim3(D_ / 64, 3 * H_), 256, 0, stream>>>(w, wT);
    proj_mfma_kernel<<<dim3(T_ / 128, 48), 256, 0, stream>>>(xT, wT, qk, vT);
    attn_mfma_kernel<<<dim3(T_ / 128, BH_), 256, 0, stream>>>(qk, vT, out);
}